// Round 10
// baseline (120.400 us; speedup 1.0000x reference)
//
#include <hip/hip_runtime.h>
#include <hip/hip_bf16.h>
#include <cstdint>
#include <cstddef>

// ---------------------------------------------------------------------------
// ResiduesNetwork: 2-layer GNN per protein + all-pairs MLP.
// R10 restructure: GNN aggregation moved to INPUT space (linearity:
// gather(Z@Wnr)/n = (gather(Z)/n)@Wnr) so each layer is ONE concat-K GEMM
// with relu fused in the epilogue -> no f32 intermediate, no split-K
// partials, 6 graph nodes total.
// Phase-1 GEMMs: split bf16 (hi+lo, 3 MFMA per operand pair) ~f32 accuracy.
// Pair phase FP16 end-to-end (R7-proven, byte-identical here).
// HISTORY: (a) launch_bounds min-waves forcing spilled breg (R3/R6: 370/489MB
// scratch traffic) — never cap VGPR below demand. (b) cooperative mega-kernel
// (R8, 404us): small-grid co-residency strangles latency hiding. (c) split-K
// + separate agg/reduce nodes (R9): partial-buffer traffic ate the gains.
// ---------------------------------------------------------------------------

typedef __bf16 bf16_t;
typedef __bf16 bf16x4 __attribute__((ext_vector_type(4)));
typedef __bf16 bf16x8 __attribute__((ext_vector_type(8)));
typedef float f32x4 __attribute__((ext_vector_type(4)));
typedef _Float16 f16_t;
typedef _Float16 f16x8 __attribute__((ext_vector_type(8)));

static __device__ __forceinline__ f32x4 mfma_bf16(bf16x8 a, bf16x8 b, f32x4 c) {
  return __builtin_amdgcn_mfma_f32_16x16x32_bf16(a, b, c, 0, 0, 0);
}
static __device__ __forceinline__ f32x4 mfma_f16(f16x8 a, f16x8 b, f32x4 c) {
  return __builtin_amdgcn_mfma_f32_16x16x32_f16(a, b, c, 0, 0, 0);
}

#define N1R 800
#define NR  1600   // concat rows
#define VF  1024
#define F0  256    // conv0 out
#define F1  128    // conv1 out

// split f32 -> (hi bf16x8, lo bf16x8) from two float4
static __device__ __forceinline__ void split8(float4 va, float4 vb,
                                              bf16x8& h8, bf16x8& l8) {
  float v[8] = {va.x, va.y, va.z, va.w, vb.x, vb.y, vb.z, vb.w};
  #pragma unroll
  for (int e = 0; e < 8; ++e) {
    bf16_t h = (bf16_t)v[e];
    h8[e] = h;
    l8[e] = (bf16_t)(v[e] - (float)h);
  }
}

// ---- fused: weight conversion/transpose + fbw + input-space aggregation ----
// grid.x: [0,2625) weight jobs; [2625,4225) agg0 rows (Zagg = gatherZ/cnt).
__global__ void conv_agg(const float* __restrict__ Z1, const float* __restrict__ Z2,
                         const int* __restrict__ nb1, const int* __restrict__ nb2,
                         const float* __restrict__ Wr0, const float* __restrict__ Wnr0,
                         const float* __restrict__ Wr1, const float* __restrict__ Wnr1,
                         const float* __restrict__ fW0, const float* __restrict__ fW1,
                         const float* __restrict__ fb1, const float* __restrict__ fW2,
                         const float* __restrict__ fb2,
                         bf16_t* __restrict__ W0h, bf16_t* __restrict__ W0l,
                         bf16_t* __restrict__ W1h, bf16_t* __restrict__ W1l,
                         bf16_t* __restrict__ fAh, bf16_t* __restrict__ fAl,
                         bf16_t* __restrict__ fBh, bf16_t* __restrict__ fBl,
                         f16_t* __restrict__ fW1th, float* __restrict__ fbw,
                         bf16_t* __restrict__ Zah, bf16_t* __restrict__ Zal) {
  int wb = blockIdx.x;
  int tid = threadIdx.x;
  if (wb >= 2625) {  // ---- agg0: Zagg[r] = (sum_nb Z[nb])/cnt, bf16 hi/lo ----
    int r = wb - 2625;
    const int* nbp;
    const float* Zp;
    if (r < N1R) { nbp = nb1 + r * 10; Zp = Z1; }
    else         { nbp = nb2 + (r - N1R) * 10; Zp = Z2; }
    int c4 = tid * 4;
    float4 s = make_float4(0.f, 0.f, 0.f, 0.f);
    int cnt = 0;
    #pragma unroll
    for (int k = 0; k < 10; ++k) {
      int idx = nbp[k];
      if (idx > -1) {
        cnt++;
        float4 v = *(const float4*)(Zp + (size_t)idx * VF + c4);
        s.x += v.x; s.y += v.y; s.z += v.z; s.w += v.w;
      }
    }
    float inv = 1.f / (float)(cnt > 0 ? cnt : 1);
    float vv[4] = {s.x * inv, s.y * inv, s.z * inv, s.w * inv};
    bf16x4 h4, l4;
    #pragma unroll
    for (int e = 0; e < 4; ++e) {
      bf16_t h = (bf16_t)vv[e];
      h4[e] = h;
      l4[e] = (bf16_t)(vv[e] - (float)h);
    }
    *(bf16x4*)(Zah + (size_t)r * VF + c4) = h4;
    *(bf16x4*)(Zal + (size_t)r * VF + c4) = l4;
    return;
  }
  if (wb >= 2560 && wb < 2624) {  // fW1 [256][64] -> f16 transposed [64][256]
    int t = (wb - 2560) * 256 + tid;
    int n = t & 63;
    int k = t >> 6;
    fW1th[(n << 8) + k] = (f16_t)fW1[k * 64 + n];
    return;
  }
  if (wb == 2624) {  // epilogue-constant table: fbw[jl*8+s]=fb1/fW2 slices
    if (tid < 128) {
      int jl = tid & 15, s = tid >> 4;
      fbw[jl * 8 + s] = (s < 4) ? fb1[s * 16 + jl] : fW2[(s - 4) * 16 + jl];
    } else if (tid == 128) {
      fbw[128] = fb2[0];
    }
    return;
  }
  const float* src; bf16_t* dh; bf16_t* dl; int ld, lk, ln, b0;
  if      (wb < 1024) { src = Wr0;  ld = 256; lk = 10; ln = 8; dh = W0h;              dl = W0l;              b0 = 0;    }
  else if (wb < 2048) { src = Wnr0; ld = 256; lk = 10; ln = 8; dh = W0h + 256 * 1024; dl = W0l + 256 * 1024; b0 = 1024; }
  else if (wb < 2176) { src = Wr1;  ld = 128; lk = 8;  ln = 7; dh = W1h;              dl = W1l;              b0 = 2048; }
  else if (wb < 2304) { src = Wnr1; ld = 128; lk = 8;  ln = 7; dh = W1h + 128 * 256;  dl = W1l + 128 * 256;  b0 = 2176; }
  else if (wb < 2432) { src = fW0;             ld = 256; lk = 7; ln = 8; dh = fAh;    dl = fAl;              b0 = 2304; }
  else                { src = fW0 + 128 * 256; ld = 256; lk = 7; ln = 8; dh = fBh;    dl = fBl;              b0 = 2432; }
  int t = (wb - b0) * 256 + tid;
  int n = t & ((1 << ln) - 1);
  int k = t >> ln;
  float v = src[k * ld + n];
  bf16_t h = (bf16_t)v;
  dh[(n << lk) + k] = h;
  dl[(n << lk) + k] = (bf16_t)(v - (float)h);
}

// 6-MFMA concat step: acc += {ah,al} x {b0,b1} (3-term split, 2 col-tiles)
#define STEP6(ah, al, b0h, b0l, b1h, b1l)        \
  acc0 = mfma_bf16(ah, b0h, acc0);               \
  acc1 = mfma_bf16(ah, b1h, acc1);               \
  acc0 = mfma_bf16(al, b0h, acc0);               \
  acc1 = mfma_bf16(al, b1h, acc1);               \
  acc0 = mfma_bf16(ah, b0l, acc0);               \
  acc1 = mfma_bf16(ah, b1l, acc1);

// ---- layer-1 GEMM: H0 = relu([Z | Zagg] @ [Wr0;Wnr0]), K=2048 -------------
// grid (4, 50): 64-col x 32-row tiles; 4 waves, wave tile 16x32.
__global__ __launch_bounds__(256) void gemm_l1(
    const float* __restrict__ Z1, const float* __restrict__ Z2,
    const bf16_t* __restrict__ Zah, const bf16_t* __restrict__ Zal,
    const bf16_t* __restrict__ W0h, const bf16_t* __restrict__ W0l,
    bf16_t* __restrict__ H0h, bf16_t* __restrict__ H0l) {
  int lane = threadIdx.x & 63;
  int w = threadIdx.x >> 6;
  int wr = w >> 1, wc = w & 1;
  int jl = lane & 15, hi = lane >> 4;

  int row0 = blockIdx.y * 32 + wr * 16;
  int col0 = blockIdx.x * 64 + wc * 32;
  int r = row0 + jl;
  int c0 = col0 + jl, c1 = col0 + 16 + jl;

  const float* pZ = ((r < N1R) ? Z1 + (size_t)r * VF
                               : Z2 + (size_t)(r - N1R) * VF) + hi * 8;
  const bf16_t* pAh = Zah + (size_t)r * VF + hi * 8;
  const bf16_t* pAl = Zal + (size_t)r * VF + hi * 8;
  const bf16_t* pB0h = W0h + (size_t)c0 * 1024 + hi * 8;
  const bf16_t* pB1h = W0h + (size_t)c1 * 1024 + hi * 8;
  const bf16_t* pB0l = W0l + (size_t)c0 * 1024 + hi * 8;
  const bf16_t* pB1l = W0l + (size_t)c1 * 1024 + hi * 8;
  const size_t OFF = (size_t)256 * 1024;  // Wnr0t half

  f32x4 acc0 = {}, acc1 = {};
  // k in [0,1024): A = Z (f32, on-the-fly split), B = Wr0t
  for (int kb = 0; kb < 1024; kb += 32) {
    bf16x8 ah, al;
    split8(*(const float4*)(pZ + kb), *(const float4*)(pZ + kb + 4), ah, al);
    bf16x8 b0h = *(const bf16x8*)(pB0h + kb);
    bf16x8 b1h = *(const bf16x8*)(pB1h + kb);
    bf16x8 b0l = *(const bf16x8*)(pB0l + kb);
    bf16x8 b1l = *(const bf16x8*)(pB1l + kb);
    STEP6(ah, al, b0h, b0l, b1h, b1l)
  }
  // k in [1024,2048): A = Zagg (bf16 hi/lo), B = Wnr0t
  for (int kb = 0; kb < 1024; kb += 32) {
    bf16x8 ah = *(const bf16x8*)(pAh + kb);
    bf16x8 al = *(const bf16x8*)(pAl + kb);
    bf16x8 b0h = *(const bf16x8*)(pB0h + OFF + kb);
    bf16x8 b1h = *(const bf16x8*)(pB1h + OFF + kb);
    bf16x8 b0l = *(const bf16x8*)(pB0l + OFF + kb);
    bf16x8 b1l = *(const bf16x8*)(pB1l + OFF + kb);
    STEP6(ah, al, b0h, b0l, b1h, b1l)
  }

  // epilogue: relu, emit bf16 hi/lo
  f32x4 accs[2] = {acc0, acc1};
  #pragma unroll
  for (int nn = 0; nn < 2; ++nn) {
    int col = col0 + nn * 16 + jl;
    #pragma unroll
    for (int reg = 0; reg < 4; ++reg) {
      int row = row0 + hi * 4 + reg;
      float v = fmaxf(accs[nn][reg], 0.f);
      bf16_t h = (bf16_t)v;
      H0h[(size_t)row * F0 + col] = h;
      H0l[(size_t)row * F0 + col] = (bf16_t)(v - (float)h);
    }
  }
}

// ---- agg1: H0agg[r] = (sum_nb H0[nb])/cnt, bf16 hi/lo ----------------------
__global__ void agg1_kernel(const bf16_t* __restrict__ H0h, const bf16_t* __restrict__ H0l,
                            const int* __restrict__ nb1, const int* __restrict__ nb2,
                            bf16_t* __restrict__ Gah, bf16_t* __restrict__ Gal) {
  int r = blockIdx.x;
  int c = threadIdx.x;
  const int* nbp;
  int roff;
  if (r < N1R) { nbp = nb1 + r * 10; roff = 0; }
  else         { nbp = nb2 + (r - N1R) * 10; roff = N1R; }
  float s = 0.f; int cnt = 0;
  #pragma unroll
  for (int k = 0; k < 10; ++k) {
    int idx = nbp[k];
    if (idx > -1) {
      cnt++;
      size_t o = (size_t)(roff + idx) * F0 + c;
      s += (float)H0h[o] + (float)H0l[o];
    }
  }
  float v = s / (float)(cnt > 0 ? cnt : 1);
  bf16_t h = (bf16_t)v;
  Gah[(size_t)r * F0 + c] = h;
  Gal[(size_t)r * F0 + c] = (bf16_t)(v - (float)h);
}

// ---- layer-2 GEMM: H1 = relu([H0 | H0agg] @ [Wr1;Wnr1]), K=512, N=128 -----
// grid (2, 50): 64-col x 32-row tiles.
__global__ __launch_bounds__(256) void gemm_l2(
    const bf16_t* __restrict__ H0h, const bf16_t* __restrict__ H0l,
    const bf16_t* __restrict__ Gah, const bf16_t* __restrict__ Gal,
    const bf16_t* __restrict__ W1h, const bf16_t* __restrict__ W1l,
    bf16_t* __restrict__ H1h, bf16_t* __restrict__ H1l) {
  int lane = threadIdx.x & 63;
  int w = threadIdx.x >> 6;
  int wr = w >> 1, wc = w & 1;
  int jl = lane & 15, hi = lane >> 4;

  int row0 = blockIdx.y * 32 + wr * 16;
  int col0 = blockIdx.x * 64 + wc * 32;
  int r = row0 + jl;
  int c0 = col0 + jl, c1 = col0 + 16 + jl;

  const bf16_t* pAh = H0h + (size_t)r * F0 + hi * 8;
  const bf16_t* pAl = H0l + (size_t)r * F0 + hi * 8;
  const bf16_t* pGh = Gah + (size_t)r * F0 + hi * 8;
  const bf16_t* pGl = Gal + (size_t)r * F0 + hi * 8;
  const bf16_t* pB0h = W1h + (size_t)c0 * 256 + hi * 8;
  const bf16_t* pB1h = W1h + (size_t)c1 * 256 + hi * 8;
  const bf16_t* pB0l = W1l + (size_t)c0 * 256 + hi * 8;
  const bf16_t* pB1l = W1l + (size_t)c1 * 256 + hi * 8;
  const size_t OFF = (size_t)128 * 256;  // Wnr1t half

  f32x4 acc0 = {}, acc1 = {};
  for (int kb = 0; kb < 256; kb += 32) {
    bf16x8 ah = *(const bf16x8*)(pAh + kb);
    bf16x8 al = *(const bf16x8*)(pAl + kb);
    bf16x8 b0h = *(const bf16x8*)(pB0h + kb);
    bf16x8 b1h = *(const bf16x8*)(pB1h + kb);
    bf16x8 b0l = *(const bf16x8*)(pB0l + kb);
    bf16x8 b1l = *(const bf16x8*)(pB1l + kb);
    STEP6(ah, al, b0h, b0l, b1h, b1l)
  }
  for (int kb = 0; kb < 256; kb += 32) {
    bf16x8 ah = *(const bf16x8*)(pGh + kb);
    bf16x8 al = *(const bf16x8*)(pGl + kb);
    bf16x8 b0h = *(const bf16x8*)(pB0h + OFF + kb);
    bf16x8 b1h = *(const bf16x8*)(pB1h + OFF + kb);
    bf16x8 b0l = *(const bf16x8*)(pB0l + OFF + kb);
    bf16x8 b1l = *(const bf16x8*)(pB1l + OFF + kb);
    STEP6(ah, al, b0h, b0l, b1h, b1l)
  }

  f32x4 accs[2] = {acc0, acc1};
  #pragma unroll
  for (int nn = 0; nn < 2; ++nn) {
    int col = col0 + nn * 16 + jl;
    #pragma unroll
    for (int reg = 0; reg < 4; ++reg) {
      int row = row0 + hi * 4 + reg;
      float v = fmaxf(accs[nn][reg], 0.f);
      bf16_t h = (bf16_t)v;
      H1h[(size_t)row * F1 + col] = h;
      H1l[(size_t)row * F1 + col] = (bf16_t)(v - (float)h);
    }
  }
}

// ---- generic split-bf16 GEMM body (64x64 tile, f16 out) for dual ----------
static __device__ __forceinline__ void gemm_body(
    const bf16_t* __restrict__ Ah, const bf16_t* __restrict__ Al,
    const bf16_t* __restrict__ Bth, const bf16_t* __restrict__ Btl,
    const float* __restrict__ bias, f16_t* __restrict__ Ch,
    int M, int N, int K, int row0b, int col0b) {
  int lane = threadIdx.x & 63;
  int w = threadIdx.x >> 6;
  int wr = w >> 1, wc = w & 1;
  int jl = lane & 15, hi = lane >> 4;

  int row0 = row0b + wr * 32;
  int col0 = col0b + wc * 32;

  int r0 = min(row0 + jl, M - 1);
  int r1 = min(row0 + 16 + jl, M - 1);
  int c0 = col0 + jl;
  int c1 = col0 + 16 + jl;

  const bf16_t* pA0h = Ah + (size_t)r0 * K + hi * 8;
  const bf16_t* pA1h = Ah + (size_t)r1 * K + hi * 8;
  const bf16_t* pA0l = Al + (size_t)r0 * K + hi * 8;
  const bf16_t* pA1l = Al + (size_t)r1 * K + hi * 8;
  const bf16_t* pB0h = Bth + (size_t)c0 * K + hi * 8;
  const bf16_t* pB1h = Bth + (size_t)c1 * K + hi * 8;
  const bf16_t* pB0l = Btl + (size_t)c0 * K + hi * 8;
  const bf16_t* pB1l = Btl + (size_t)c1 * K + hi * 8;

  f32x4 acc[2][2] = {};
  for (int kb = 0; kb < K; kb += 32) {
    bf16x8 a0h = *(const bf16x8*)(pA0h + kb);
    bf16x8 a1h = *(const bf16x8*)(pA1h + kb);
    bf16x8 a0l = *(const bf16x8*)(pA0l + kb);
    bf16x8 a1l = *(const bf16x8*)(pA1l + kb);
    bf16x8 b0h = *(const bf16x8*)(pB0h + kb);
    bf16x8 b1h = *(const bf16x8*)(pB1h + kb);
    bf16x8 b0l = *(const bf16x8*)(pB0l + kb);
    bf16x8 b1l = *(const bf16x8*)(pB1l + kb);

    acc[0][0] = mfma_bf16(a0h, b0h, acc[0][0]);
    acc[0][1] = mfma_bf16(a0h, b1h, acc[0][1]);
    acc[1][0] = mfma_bf16(a1h, b0h, acc[1][0]);
    acc[1][1] = mfma_bf16(a1h, b1h, acc[1][1]);

    acc[0][0] = mfma_bf16(a0l, b0h, acc[0][0]);
    acc[0][1] = mfma_bf16(a0l, b1h, acc[0][1]);
    acc[1][0] = mfma_bf16(a1l, b0h, acc[1][0]);
    acc[1][1] = mfma_bf16(a1l, b1h, acc[1][1]);

    acc[0][0] = mfma_bf16(a0h, b0l, acc[0][0]);
    acc[0][1] = mfma_bf16(a0h, b1l, acc[0][1]);
    acc[1][0] = mfma_bf16(a1h, b0l, acc[1][0]);
    acc[1][1] = mfma_bf16(a1h, b1l, acc[1][1]);
  }

  #pragma unroll
  for (int m = 0; m < 2; ++m) {
    #pragma unroll
    for (int nn = 0; nn < 2; ++nn) {
      int col = col0 + nn * 16 + jl;
      float bv = bias ? bias[col] : 0.f;
      #pragma unroll
      for (int reg = 0; reg < 4; ++reg) {
        int row = row0 + m * 16 + hi * 4 + reg;
        if (row < M) Ch[(size_t)row * N + col] = (f16_t)(acc[m][nn][reg] + bv);
      }
    }
  }
}

// dual GEMM -> f16: A' = x1@fW0top + fb0 ; B = x2@fW0bot (one launch).
__global__ __launch_bounds__(256) void gemm_dual(
    const bf16_t* __restrict__ H1h, const bf16_t* __restrict__ H1l,
    const bf16_t* __restrict__ fAh, const bf16_t* __restrict__ fAl,
    const bf16_t* __restrict__ fBh, const bf16_t* __restrict__ fBl,
    const float* __restrict__ fb0, f16_t* __restrict__ ABh) {
  int part = blockIdx.y / 13;
  int my = blockIdx.y % 13;
  gemm_body(H1h + (size_t)part * N1R * F1, H1l + (size_t)part * N1R * F1,
            part ? fBh : fAh, part ? fBl : fAl, part ? nullptr : fb0,
            ABh + (size_t)part * N1R * 256, N1R, 256, F1,
            my * 64, blockIdx.x * 64);
}

// ---- pair kernel (FP16, R7-proven): out = fb2 + relu(relu(A'+B)@fW1+fb1).fW2
#define IBLK 2
#define ITILE 16
__global__ __launch_bounds__(256) void pair_kernel(
    const f16_t* __restrict__ ABh, const f16_t* __restrict__ W1th,
    const float* __restrict__ fbw, float* __restrict__ out) {
  __shared__ alignas(16) unsigned char sWh[64 * 512];   // [n][512B] swizzled
  __shared__ alignas(16) f16_t sA[ITILE * 256];         // 8KB

  const int tid = threadIdx.x;
  const int lane = tid & 63;
  const int w = tid >> 6;
  const int jl = lane & 15;
  const int hi = lane >> 4;
  const int j0 = blockIdx.x * 64;
  const int i0 = blockIdx.y * ITILE;

  // stage fW1t f16 [64][256] -> LDS, swizzle byte^=((n&7)<<4) in-row
  #pragma unroll
  for (int s = 0; s < 8; ++s) {
    int c = tid + 256 * s;
    int n = c >> 5;
    int cb = (c & 31) << 4;
    int sw = cb ^ ((n & 7) << 4);
    *(uint4*)(sWh + n * 512 + sw) = *(const uint4*)((const unsigned char*)W1th + n * 512 + cb);
  }
  // stage A' rows i0..i0+15 (f16): 512 x 16B chunks, 32 per row
  #pragma unroll
  for (int s = 0; s < 2; ++s) {
    int c = tid + 256 * s;
    int rr = c >> 5;
    int cc = c & 31;
    *(uint4*)((unsigned char*)sA + rr * 512 + cc * 16) =
        *(const uint4*)(ABh + (size_t)(i0 + rr) * 256 + cc * 8);
  }

  // B row of this lane's pair -> registers (its k-slice: 64 f16 = 32 VGPR)
  int j = j0 + w * 16 + jl;
  f16x8 breg[8];
  {
    const f16_t* Bp = ABh + (size_t)(N1R + j) * 256;
    bool ok = (j < N1R);
    f16x8 z{};
    #pragma unroll
    for (int t = 0; t < 8; ++t)
      breg[t] = ok ? *(const f16x8*)(Bp + t * 32 + hi * 8) : z;
  }

  // epilogue constants: 2 vector loads from pre-transposed table
  float4 fb1r = *(const float4*)(fbw + jl * 8);
  float4 fw2r = *(const float4*)(fbw + jl * 8 + 4);
  float bias2 = fbw[128];

  __syncthreads();

  #pragma unroll 1
  for (int ig = 0; ig < ITILE / IBLK; ++ig) {
    f32x4 acc[IBLK][4] = {};
    #pragma unroll
    for (int t = 0; t < 8; ++t) {
      f16x8 bv = breg[t];
      f16x8 af[IBLK];
      const f16x8 Zv{};
      #pragma unroll
      for (int ib = 0; ib < IBLK; ++ib) {
        f16x8 av = *(const f16x8*)(sA + (ig * IBLK + ib) * 256 + t * 32 + hi * 8);
        af[ib] = __builtin_elementwise_max(av + bv, Zv);  // pk_add + pk_max
      }
      int kbyte = t * 64 + hi * 16;
      #pragma unroll
      for (int nf = 0; nf < 4; ++nf) {
        int n = nf * 16 + jl;
        f16x8 wh = *(const f16x8*)(sWh + n * 512 + (kbyte ^ ((n & 7) << 4)));
        #pragma unroll
        for (int ib = 0; ib < IBLK; ++ib)
          acc[ib][nf] = mfma_f16(af[ib], wh, acc[ib][nf]);
      }
    }
    // epilogue: h1 = relu(acc + fb1); out = h1 . fW2 + fb2
    float fb1a[4] = {fb1r.x, fb1r.y, fb1r.z, fb1r.w};
    float fw2a[4] = {fw2r.x, fw2r.y, fw2r.z, fw2r.w};
    #pragma unroll
    for (int ib = 0; ib < IBLK; ++ib) {
      float part[4];
      #pragma unroll
      for (int r = 0; r < 4; ++r) {
        float ssum = 0.f;
        #pragma unroll
        for (int nf = 0; nf < 4; ++nf) {
          float h = acc[ib][nf][r] + fb1a[nf];
          h = fmaxf(h, 0.f);
          ssum += h * fw2a[nf];
        }
        part[r] = ssum;
      }
      #pragma unroll
      for (int off = 1; off < 16; off <<= 1) {
        #pragma unroll
        for (int r = 0; r < 4; ++r) part[r] += __shfl_xor(part[r], off, 64);
      }
      if (jl == 0) {
        int jo = j0 + w * 16 + hi * 4;
        if (jo < N1R) {
          float4 o = make_float4(part[0] + bias2, part[1] + bias2,
                                 part[2] + bias2, part[3] + bias2);
          *(float4*)(out + (size_t)(i0 + ig * IBLK + ib) * 800 + jo) = o;
        }
      }
    }
  }
}

// ---------------------------------------------------------------------------
extern "C" void kernel_launch(void* const* d_in, const int* in_sizes, int n_in,
                              void* d_out, int out_size, void* d_ws, size_t ws_size,
                              hipStream_t stream) {
  const float* Z1   = (const float*)d_in[0];
  const int*   nb1  = (const int*)d_in[1];
  const float* Z2   = (const float*)d_in[2];
  const int*   nb2  = (const int*)d_in[3];
  const float* Wr0  = (const float*)d_in[4];
  const float* Wnr0 = (const float*)d_in[5];
  const float* Wr1  = (const float*)d_in[6];
  const float* Wnr1 = (const float*)d_in[7];
  const float* fW0  = (const float*)d_in[8];
  const float* fb0  = (const float*)d_in[9];
  const float* fW1  = (const float*)d_in[10];
  const float* fb1  = (const float*)d_in[11];
  const float* fW2  = (const float*)d_in[12];
  const float* fb2  = (const float*)d_in[13];
  float* out = (float*)d_out;

  // workspace carve
  char* p = (char*)d_ws;
  auto alloc = [&](size_t bytes) {
    char* q = p;
    p += (bytes + 255) & ~(size_t)255;
    return q;
  };
  bf16_t* W0h   = (bf16_t*)alloc((size_t)512 * 1024 * 2);
  bf16_t* W0l   = (bf16_t*)alloc((size_t)512 * 1024 * 2);
  bf16_t* W1h   = (bf16_t*)alloc((size_t)256 * 256 * 2);
  bf16_t* W1l   = (bf16_t*)alloc((size_t)256 * 256 * 2);
  bf16_t* fAh   = (bf16_t*)alloc((size_t)256 * 128 * 2);
  bf16_t* fAl   = (bf16_t*)alloc((size_t)256 * 128 * 2);
  bf16_t* fBh   = (bf16_t*)alloc((size_t)256 * 128 * 2);
  bf16_t* fBl   = (bf16_t*)alloc((size_t)256 * 128 * 2);
  f16_t*  fW1th = (f16_t*)alloc((size_t)64 * 256 * 2);
  float*  fbw   = (float*)alloc(129 * 4);
  bf16_t* Zah   = (bf16_t*)alloc((size_t)NR * VF * 2);
  bf16_t* Zal   = (bf16_t*)alloc((size_t)NR * VF * 2);
  bf16_t* H0h   = (bf16_t*)alloc((size_t)NR * F0 * 2);
  bf16_t* H0l   = (bf16_t*)alloc((size_t)NR * F0 * 2);
  bf16_t* Gah   = (bf16_t*)alloc((size_t)NR * F0 * 2);
  bf16_t* Gal   = (bf16_t*)alloc((size_t)NR * F0 * 2);
  bf16_t* H1h   = (bf16_t*)alloc((size_t)NR * F1 * 2);
  bf16_t* H1l   = (bf16_t*)alloc((size_t)NR * F1 * 2);
  f16_t*  ABh   = (f16_t*)alloc((size_t)NR * 256 * 2);
  (void)in_sizes; (void)n_in; (void)out_size; (void)ws_size;

  // 1. weight conversion + fbw + input-space aggregation (one launch)
  conv_agg<<<4225, 256, 0, stream>>>(Z1, Z2, nb1, nb2, Wr0, Wnr0, Wr1, Wnr1,
                                     fW0, fW1, fb1, fW2, fb2,
                                     W0h, W0l, W1h, W1l, fAh, fAl, fBh, fBl,
                                     fW1th, fbw, Zah, Zal);
  // 2. layer-1 concat-K GEMM + relu -> H0 (bf16 hi/lo)
  gemm_l1<<<dim3(4, 50), 256, 0, stream>>>(Z1, Z2, Zah, Zal, W0h, W0l, H0h, H0l);
  // 3. H0 aggregation (input space for layer 2)
  agg1_kernel<<<NR, 256, 0, stream>>>(H0h, H0l, nb1, nb2, Gah, Gal);
  // 4. layer-2 concat-K GEMM + relu -> H1 (bf16 hi/lo)
  gemm_l2<<<dim3(2, 50), 256, 0, stream>>>(H0h, H0l, Gah, Gal, W1h, W1l, H1h, H1l);
  // 5. A' and B in one launch -> f16
  gemm_dual<<<dim3(4, 26), 256, 0, stream>>>(H1h, H1l, fAh, fAl, fBh, fBl, fb0, ABh);
  // 6. all-pairs fused MLP (fp16 datapath)
  pair_kernel<<<dim3(13, 50), 256, 0, stream>>>(ABh, fW1th, fbw, out);
}